// Round 1
// baseline (47.048 us; speedup 1.0000x reference)
//
#include <hip/hip_runtime.h>

#define NCH   85    // 80 cls + 4 bbox + 1 ctr
#define TILE  100   // positions per block; divides every HW (25600,6400,1600,400,100)
#define LS    101   // LDS row stride in floats (odd -> bank-conflict-free column reads)
#define OUTCH 87    // 2 coord + 80 scores + 4 bbox + 1 ctr

__global__ __launch_bounds__(256) void fcos_filter_kernel(
    const float* __restrict__ c0, const float* __restrict__ b0, const float* __restrict__ t0,
    const float* __restrict__ c1, const float* __restrict__ b1, const float* __restrict__ t1,
    const float* __restrict__ c2, const float* __restrict__ b2, const float* __restrict__ t2,
    const float* __restrict__ c3, const float* __restrict__ b3, const float* __restrict__ t3,
    const float* __restrict__ c4, const float* __restrict__ b4, const float* __restrict__ t4,
    float* __restrict__ out)
{
    __shared__ float lds[NCH * LS];   // 85*101*4 = 34,340 B
    __shared__ float s_mask[TILE];
    __shared__ float s_cx[TILE];
    __shared__ float s_cy[TILE];

    const int bid = blockIdx.x;
    const int tid = threadIdx.x;

    // ---- level decode (compile-time constants per branch) ----
    const float *cls, *bbx, *ctr;
    int bl, HW, W, str, sh;
    size_t obase;
    if (bid < 2048)      { bl = bid;        cls=c0; bbx=b0; ctr=t0; HW=25600; W=160; str=8;   sh=8; obase=0u;        }
    else if (bid < 2560) { bl = bid - 2048; cls=c1; bbx=b1; ctr=t1; HW=6400;  W=80;  str=16;  sh=6; obase=17817600u; }
    else if (bid < 2688) { bl = bid - 2560; cls=c2; bbx=b2; ctr=t2; HW=1600;  W=40;  str=32;  sh=4; obase=22272000u; }
    else if (bid < 2720) { bl = bid - 2688; cls=c3; bbx=b3; ctr=t3; HW=400;   W=20;  str=64;  sh=2; obase=23385600u; }
    else                 { bl = bid - 2720; cls=c4; bbx=b4; ctr=t4; HW=100;   W=10;  str=128; sh=0; obase=23664000u; }

    const int img  = bl >> sh;                 // image index within batch
    const int tile = bl & ((1 << sh) - 1);     // tile index within image
    const int p0   = tile * TILE;              // first position of this tile

    // ---- Phase A: global -> LDS, float4 coalesced along positions ----
    for (int idx = tid; idx < NCH * (TILE / 4); idx += 256) {
        const int c = idx / 25;          // channel 0..84 (compile-time magic div)
        const int q = idx - c * 25;      // float4 index within the 100-position row
        const float* src;
        if (c < 80)      src = cls + (size_t)(img * 80 + c) * HW;
        else if (c < 84) src = bbx + (size_t)(img * 4 + (c - 80)) * HW;
        else             src = ctr + (size_t)img * HW;
        const float4 v = *reinterpret_cast<const float4*>(src + p0 + 4 * q);
        const int a = c * LS + 4 * q;
        lds[a + 0] = v.x; lds[a + 1] = v.y; lds[a + 2] = v.z; lds[a + 3] = v.w;
    }
    __syncthreads();

    // ---- Phase B: per-position mask (max over 80 class scores) + coords ----
    if (tid < TILE) {
        float m0 = lds[0 * LS + tid];
        float m1 = lds[1 * LS + tid];
        float m2 = lds[2 * LS + tid];
        float m3 = lds[3 * LS + tid];
        #pragma unroll
        for (int c = 4; c < 80; c += 4) {
            m0 = fmaxf(m0, lds[(c + 0) * LS + tid]);
            m1 = fmaxf(m1, lds[(c + 1) * LS + tid]);
            m2 = fmaxf(m2, lds[(c + 2) * LS + tid]);
            m3 = fmaxf(m3, lds[(c + 3) * LS + tid]);
        }
        const float mx   = fmaxf(fmaxf(m0, m1), fmaxf(m2, m3));
        const float mask = (mx > 0.5f) ? 1.0f : 0.0f;
        const int pg = p0 + tid;
        const int y  = pg / W;          // W is per-level; runs once per block
        const int x  = pg - y * W;
        s_mask[tid] = mask;
        s_cx[tid]   = (float)(x * str + (str >> 1)) * mask;
        s_cy[tid]   = (float)(y * str + (str >> 1)) * mask;
    }
    __syncthreads();

    // ---- Phase C: LDS -> global; block writes a fully contiguous 8700-float chunk ----
    float* dst = out + obase + ((size_t)img * HW + p0) * OUTCH;
    for (int e = tid; e < TILE * OUTCH; e += 256) {
        const int p  = e / OUTCH;       // magic-mul division by 87
        const int ch = e - p * OUTCH;
        float v;
        if (ch >= 2) v = lds[(ch - 2) * LS + p] * s_mask[p];
        else         v = (ch == 0) ? s_cx[p] : s_cy[p];
        dst[e] = v;
    }
}

extern "C" void kernel_launch(void* const* d_in, const int* in_sizes, int n_in,
                              void* d_out, int out_size, void* d_ws, size_t ws_size,
                              hipStream_t stream) {
    (void)in_sizes; (void)n_in; (void)out_size; (void)d_ws; (void)ws_size;
    fcos_filter_kernel<<<2728, 256, 0, stream>>>(
        (const float*)d_in[0],  (const float*)d_in[1],  (const float*)d_in[2],
        (const float*)d_in[3],  (const float*)d_in[4],  (const float*)d_in[5],
        (const float*)d_in[6],  (const float*)d_in[7],  (const float*)d_in[8],
        (const float*)d_in[9],  (const float*)d_in[10], (const float*)d_in[11],
        (const float*)d_in[12], (const float*)d_in[13], (const float*)d_in[14],
        (float*)d_out);
}

// Round 3
// 35.248 us; speedup vs baseline: 1.3348x; 1.3348x over previous
//
#include <hip/hip_runtime.h>

#define NCH   85   // 80 cls + 4 bbox + 1 ctr
#define TILE  64   // positions per block
#define LS    67   // LDS row stride: 67%32=3, odd -> conflict-free A-writes and C-reads
#define OUTCH 87   // 2 coord + 80 scores + 4 bbox + 1 ctr

__global__ __launch_bounds__(256) void fcos_filter_kernel(
    const float* __restrict__ c0, const float* __restrict__ b0, const float* __restrict__ t0,
    const float* __restrict__ c1, const float* __restrict__ b1, const float* __restrict__ t1,
    const float* __restrict__ c2, const float* __restrict__ b2, const float* __restrict__ t2,
    const float* __restrict__ c3, const float* __restrict__ b3, const float* __restrict__ t3,
    const float* __restrict__ c4, const float* __restrict__ b4, const float* __restrict__ t4,
    float* __restrict__ out)
{
    __shared__ float lds[NCH * LS];   // 85*67*4 = 22,780 B
    __shared__ float s_flag[TILE];    // +256 B -> 23,036 B -> 7 blocks/CU

    const int bid = blockIdx.x;
    const int tid = threadIdx.x;

    // ---- level decode; img/tile divisions are by per-branch constants ----
    const float *cls, *bbx, *ctr;
    int img, tile, HW, W, str, ksh;
    size_t obase;
    if (bid < 3200)      { cls=c0; bbx=b0; ctr=t0; HW=25600; W=160; str=8;   ksh=4; obase=0u;
                           img = bid / 400;          tile = bid - img * 400; }
    else if (bid < 4000) { cls=c1; bbx=b1; ctr=t1; HW=6400;  W=80;  str=16;  ksh=3; obase=17817600u;
                           const int bl = bid - 3200; img = bl / 100; tile = bl - img * 100; }
    else if (bid < 4200) { cls=c2; bbx=b2; ctr=t2; HW=1600;  W=40;  str=32;  ksh=2; obase=22272000u;
                           const int bl = bid - 4000; img = bl / 25;  tile = bl - img * 25; }
    else if (bid < 4256) { cls=c3; bbx=b3; ctr=t3; HW=400;   W=20;  str=64;  ksh=1; obase=23385600u;
                           const int bl = bid - 4200; img = bl / 7;   tile = bl - img * 7; }
    else                 { cls=c4; bbx=b4; ctr=t4; HW=100;   W=10;  str=128; ksh=0; obase=23664000u;
                           const int bl = bid - 4256; img = bl >> 1;  tile = bl & 1; }

    const int p0    = tile * TILE;
    const int valid = min(TILE, HW - p0);     // <64 only in levels 3/4 tail blocks

    // zero flags before any flag-OR write
    if (tid < TILE) s_flag[tid] = 0.0f;
    __syncthreads();

    // ---- Phase A: global -> LDS + flag-OR mask ----
    const int  lane_c = tid >> 4;             // 0..15
    const int  q4     = (tid & 15) << 2;      // 0,4,...,60
    const bool qok    = q4 < valid;

    float4 v0, v1, v2, v3, v4, v5;
    const float* abase = cls + ((size_t)img * 80 + lane_c) * HW + p0 + q4;
    if (qok) {
        v0 = *reinterpret_cast<const float4*>(abase);
        v1 = *reinterpret_cast<const float4*>(abase + (size_t)16 * HW);
        v2 = *reinterpret_cast<const float4*>(abase + (size_t)32 * HW);
        v3 = *reinterpret_cast<const float4*>(abase + (size_t)48 * HW);
        v4 = *reinterpret_cast<const float4*>(abase + (size_t)64 * HW);
    }
    const bool r5 = (tid < 80) && qok;        // channels 80..84 (bbox, ctr)
    if (r5) {
        const float* s5 = (lane_c < 4)
            ? bbx + ((size_t)img * 4 + lane_c) * HW + p0 + q4
            : ctr + (size_t)img * HW + p0 + q4;
        v5 = *reinterpret_cast<const float4*>(s5);
    }

    #define PUT(base_c, V, FLAGS)                                   \
    {   const int a = (base_c + lane_c) * LS + q4;                  \
        lds[a + 0] = V.x; lds[a + 1] = V.y;                         \
        lds[a + 2] = V.z; lds[a + 3] = V.w;                         \
        if (FLAGS) {                                                \
            if (V.x > 0.5f) s_flag[q4 + 0] = 1.0f;                  \
            if (V.y > 0.5f) s_flag[q4 + 1] = 1.0f;                  \
            if (V.z > 0.5f) s_flag[q4 + 2] = 1.0f;                  \
            if (V.w > 0.5f) s_flag[q4 + 3] = 1.0f;                  \
        }                                                           \
    }

    if (qok) {
        PUT(0,  v0, true) PUT(16, v1, true) PUT(32, v2, true)
        PUT(48, v3, true) PUT(64, v4, true)
    }
    if (r5) { PUT(80, v5, false) }
    #undef PUT

    __syncthreads();

    // ---- Phase C: LDS -> global, contiguous per-block chunk ----
    float* dst = out + obase + ((size_t)img * HW + p0) * OUTCH;
    #pragma unroll 4
    for (int e = tid; e < TILE * OUTCH; e += 256) {
        const int p  = e / OUTCH;             // magic-mul div by 87
        if (p >= valid) break;                // tail guard (uniform-ish)
        const int ch = e - p * OUTCH;
        const float m = s_flag[p];
        float val;
        if (ch >= 2) {
            val = lds[(ch - 2) * LS + p] * m;
        } else {
            const int pg = p0 + p;
            const int t  = pg >> ksh;         // = pg / (W/10)
            const int y  = t / 10;            // magic-mul div by 10
            const int x  = pg - y * W;
            const int coord = (ch == 0) ? x : y;
            val = (float)(coord * str + (str >> 1)) * m;
        }
        __builtin_nontemporal_store(val, dst + e);
    }
}

extern "C" void kernel_launch(void* const* d_in, const int* in_sizes, int n_in,
                              void* d_out, int out_size, void* d_ws, size_t ws_size,
                              hipStream_t stream) {
    (void)in_sizes; (void)n_in; (void)out_size; (void)d_ws; (void)ws_size;
    fcos_filter_kernel<<<4272, 256, 0, stream>>>(
        (const float*)d_in[0],  (const float*)d_in[1],  (const float*)d_in[2],
        (const float*)d_in[3],  (const float*)d_in[4],  (const float*)d_in[5],
        (const float*)d_in[6],  (const float*)d_in[7],  (const float*)d_in[8],
        (const float*)d_in[9],  (const float*)d_in[10], (const float*)d_in[11],
        (const float*)d_in[12], (const float*)d_in[13], (const float*)d_in[14],
        (float*)d_out);
}